// Round 1
// baseline (297.635 us; speedup 1.0000x reference)
//
#include <hip/hip_runtime.h>
#include <math.h>

// Problem constants (from reference)
constexpr int L     = 2048;   // series length
constexpr int NH    = 96;     // forecast horizon / W cols
constexpr int MLEN  = 150;    // AR2 fit window
constexpr int NAR   = 148;    // number of AR2 regression terms
constexpr float LAM    = 0.001f;
constexpr float CLIP_K = 4.0f;

// Tiling
constexpr int TM = 32;        // rows per block
constexpr int BK = 32;        // K tile

// Block: 256 threads = 16x16 micro-grid; each thread computes 2 rows x 6 cols.
// Staging: thread t loads one float4 of X row (t>>3), k-offset (t&7)*4 -> fully
// coalesced 128B segments, and each 8-thread group owns exactly one row for the
// per-row sum/sumsq accumulation (shuffle-xor reduce over 8 lanes at the end).
__global__ __launch_bounds__(256, 2) void fused_ar2_kernel(
    const float* __restrict__ x, const float* __restrict__ W,
    float* __restrict__ out)
{
    __shared__ float Xs[TM][BK + 4];     // +4 pad: row stride 36 = 4 mod 32 banks
    __shared__ float Ws[BK][NH];
    __shared__ float Ys[TM][NH + 1];     // +1 pad: recurrence writes stride-97
    __shared__ float lo_s[TM], hi_s[TM];

    const int t    = threadIdx.x;
    const int row0 = blockIdx.x * TM;

    const int sr = t >> 3;               // staged row (0..31)
    const int sk = (t & 7) << 2;         // staged k offset (float4)
    const float* xrow = x + (size_t)(row0 + sr) * L;

    const int ti = t >> 4;               // 0..15 -> rows 2*ti, 2*ti+1
    const int tj = t & 15;               // 0..15 -> cols 6*tj .. 6*tj+5

    float acc[2][6];
    #pragma unroll
    for (int r = 0; r < 2; ++r)
        #pragma unroll
        for (int c = 0; c < 6; ++c) acc[r][c] = 0.f;

    float sum = 0.f, sumsq = 0.f;

    for (int k0 = 0; k0 < L; k0 += BK) {
        // --- stage X tile (and accumulate row stats on the fly) ---
        float4 xv = *(const float4*)(xrow + k0 + sk);
        sum   += (xv.x + xv.y) + (xv.z + xv.w);
        sumsq += xv.x * xv.x + xv.y * xv.y + xv.z * xv.z + xv.w * xv.w;
        *(float4*)(&Xs[sr][sk]) = xv;

        // --- stage W tile: 32x96 floats = 768 float4s, 3 per thread, coalesced ---
        #pragma unroll
        for (int i = 0; i < 3; ++i) {
            int idx = t + 256 * i;             // 0..767
            int kk  = idx / 24;                // magic-mul
            int rem = idx - kk * 24;
            *(float4*)(&Ws[kk][rem << 2]) =
                *(const float4*)(W + (size_t)(k0 + kk) * NH + (rem << 2));
        }
        __syncthreads();

        // --- 2x6 micro-tile FMA over the K tile ---
        #pragma unroll
        for (int kk = 0; kk < BK; ++kk) {
            float x0 = Xs[2 * ti    ][kk];
            float x1 = Xs[2 * ti + 1][kk];
            #pragma unroll
            for (int c = 0; c < 6; ++c) {
                float w = Ws[kk][6 * tj + c];
                acc[0][c] = fmaf(x0, w, acc[0][c]);
                acc[1][c] = fmaf(x1, w, acc[1][c]);
            }
        }
        __syncthreads();
    }

    // --- per-row stats: reduce sum/sumsq over the 8 lanes sharing row sr ---
    #pragma unroll
    for (int off = 4; off >= 1; off >>= 1) {
        sum   += __shfl_xor(sum,   off);
        sumsq += __shfl_xor(sumsq, off);
    }

    // --- AR2 normal-equation sums over the last-150 tail (L2-hot) ---
    const float* ytail = xrow + (L - MLEN);   // y[0..149]
    float A11 = 0.f, A22 = 0.f, A12 = 0.f, b1 = 0.f, b2 = 0.f;
    for (int i = (t & 7); i < NAR; i += 8) {
        float p2v = ytail[i];        // y[i]
        float p1v = ytail[i + 1];    // y[i+1]
        float Yv  = ytail[i + 2];    // y[i+2]
        A11 = fmaf(p1v, p1v, A11);
        A22 = fmaf(p2v, p2v, A22);
        A12 = fmaf(p1v, p2v, A12);
        b1  = fmaf(p1v, Yv,  b1);
        b2  = fmaf(p2v, Yv,  b2);
    }
    #pragma unroll
    for (int off = 4; off >= 1; off >>= 1) {
        A11 += __shfl_xor(A11, off);
        A22 += __shfl_xor(A22, off);
        A12 += __shfl_xor(A12, off);
        b1  += __shfl_xor(b1,  off);
        b2  += __shfl_xor(b2,  off);
    }

    if ((t & 7) == 0) {
        A11 += LAM;
        A22 += LAM;
        float det = A11 * A22 - A12 * A12;
        float a1  = (b1 * A22 - b2 * A12) / det;
        float a2  = (A11 * b2 - A12 * b1) / det;

        float last = ytail[MLEN - 1];     // x[..,-1]
        float y1 = last;
        float y2 = ytail[MLEN - 2];       // x[..,-2]
        for (int n = 0; n < NH; ++n) {
            float yn = a1 * y1 + a2 * y2;
            Ys[sr][n] = yn;
            y2 = y1; y1 = yn;
        }

        float var  = (sumsq - sum * sum * (1.0f / L)) * (1.0f / (L - 1));
        float hstd = fmaxf(sqrtf(fmaxf(var, 0.f)), 1e-6f);
        lo_s[sr] = last - CLIP_K * hstd;
        hi_s[sr] = last + CLIP_K * hstd;
    }
    __syncthreads();

    // --- epilogue: out = clip(Yb + d_hat, lo, hi) ---
    #pragma unroll
    for (int r = 0; r < 2; ++r) {
        int rr = 2 * ti + r;
        float lo = lo_s[rr], hi = hi_s[rr];
        float* orow = out + (size_t)(row0 + rr) * NH + 6 * tj;
        #pragma unroll
        for (int c = 0; c < 6; ++c) {
            float v = Ys[rr][6 * tj + c] + acc[r][c];
            orow[c] = fminf(fmaxf(v, lo), hi);
        }
    }
}

extern "C" void kernel_launch(void* const* d_in, const int* in_sizes, int n_in,
                              void* d_out, int out_size, void* d_ws, size_t ws_size,
                              hipStream_t stream) {
    const float* x = (const float*)d_in[0];   // (32,512,2048) fp32
    const float* W = (const float*)d_in[1];   // (2048,96) fp32
    float* out = (float*)d_out;               // (32,512,96) fp32

    const int rows = 32 * 512;                // 16384
    dim3 grid(rows / TM);                     // 512 blocks
    dim3 block(256);
    fused_ar2_kernel<<<grid, block, 0, stream>>>(x, W, out);
}

// Round 2
// 228.915 us; speedup vs baseline: 1.3002x; 1.3002x over previous
//
#include <hip/hip_runtime.h>
#include <math.h>

// Problem constants (from reference)
constexpr int L     = 2048;   // series length
constexpr int NH    = 96;     // forecast horizon / W cols
constexpr int MLEN  = 150;    // AR2 fit window
constexpr int NAR   = 148;    // number of AR2 regression terms
constexpr float LAM    = 0.001f;
constexpr float CLIP_K = 4.0f;

typedef __attribute__((ext_vector_type(8))) short short8;   // 8 bf16 (4 VGPRs) MFMA A/B frag
typedef __attribute__((ext_vector_type(4))) float floatx4;  // MFMA C/D frag

// fp32 -> bf16, round-to-nearest-even (bit trick; inputs are finite/normal)
__device__ inline short f2bf(float f) {
    union { float f; unsigned u; } v; v.f = f;
    unsigned r = v.u + 0x7FFFu + ((v.u >> 16) & 1u);
    return (short)(r >> 16);
}

// Pre-kernel: Wt[n][k] = bf16(W[k][n]).  96*2048 = 196608 elements.
// Writes coalesced (consecutive k); reads are a stride-96 gather but W is
// 768 KB -> L2-resident after first lines.
__global__ __launch_bounds__(256) void wt_kernel(
    const float* __restrict__ W, short* __restrict__ Wt)
{
    int idx = blockIdx.x * 256 + threadIdx.x;   // n*2048 + k
    int n = idx >> 11;
    int k = idx & 2047;
    Wt[idx] = f2bf(W[k * NH + n]);
}

// Main kernel: one wave (64 threads) per 16-row tile; 1024 blocks.
// Per K=32 step: A frag from global x (fp32->bf16 in-register), B frags from
// precomputed bf16 Wt, 6x mfma_f32_16x16x32_bf16. No LDS in the K-loop.
// MFMA layouts (verified in docs): A[m=lane&15][k=quad*8+j];
// B[k=quad*8+j][n=lane&15]; D col=lane&15, row=quad*4+reg.
__global__ __launch_bounds__(64) void gemm_ar2_kernel(
    const float* __restrict__ x, const short* __restrict__ Wt,
    float* __restrict__ out)
{
    __shared__ float Ys[16][NH + 1];   // +1 pad: recurrence writes stride-97

    const int lane = threadIdx.x;
    const int m    = lane & 15;        // tile row (A) / tile col (B,D)
    const int quad = lane >> 4;        // k-chunk selector
    const int row0 = blockIdx.x * 16;

    const float* arow  = x  + (size_t)(row0 + m) * L + quad * 8;
    const short* wbase = Wt + (size_t)m * L + quad * 8;   // + j*16*L + k0

    floatx4 acc[6];
    #pragma unroll
    for (int j = 0; j < 6; ++j) acc[j] = floatx4{0.f, 0.f, 0.f, 0.f};

    float sum = 0.f, sumsq = 0.f;

    // Software pipeline: A prefetched 2 steps ahead (HBM stream),
    // B prefetched 1 step ahead (L2-resident).
    float4 a0_c = *(const float4*)(arow + 0);
    float4 a1_c = *(const float4*)(arow + 4);
    float4 a0_n = *(const float4*)(arow + 32);
    float4 a1_n = *(const float4*)(arow + 36);
    short8 b_c[6];
    #pragma unroll
    for (int j = 0; j < 6; ++j) b_c[j] = *(const short8*)(wbase + j * 16 * L);

    for (int step = 0; step < 64; ++step) {
        // prefetch addresses (clamped re-reads on the last steps: harmless)
        int k2 = (step + 2 < 64) ? (step + 2) * 32 : step * 32;
        int k1 = (step + 1 < 64) ? (step + 1) * 32 : step * 32;
        float4 a0_p = *(const float4*)(arow + k2);
        float4 a1_p = *(const float4*)(arow + k2 + 4);
        short8 b_n[6];
        #pragma unroll
        for (int j = 0; j < 6; ++j)
            b_n[j] = *(const short8*)(wbase + j * 16 * L + k1);

        // per-row stats on the current A data (each lane sees only row m)
        sum   += ((a0_c.x + a0_c.y) + (a0_c.z + a0_c.w))
               + ((a1_c.x + a1_c.y) + (a1_c.z + a1_c.w));
        sumsq = fmaf(a0_c.x, a0_c.x, sumsq); sumsq = fmaf(a0_c.y, a0_c.y, sumsq);
        sumsq = fmaf(a0_c.z, a0_c.z, sumsq); sumsq = fmaf(a0_c.w, a0_c.w, sumsq);
        sumsq = fmaf(a1_c.x, a1_c.x, sumsq); sumsq = fmaf(a1_c.y, a1_c.y, sumsq);
        sumsq = fmaf(a1_c.z, a1_c.z, sumsq); sumsq = fmaf(a1_c.w, a1_c.w, sumsq);

        // convert current A to bf16 frag
        short8 af;
        af[0] = f2bf(a0_c.x); af[1] = f2bf(a0_c.y);
        af[2] = f2bf(a0_c.z); af[3] = f2bf(a0_c.w);
        af[4] = f2bf(a1_c.x); af[5] = f2bf(a1_c.y);
        af[6] = f2bf(a1_c.z); af[7] = f2bf(a1_c.w);

        #pragma unroll
        for (int j = 0; j < 6; ++j)
            acc[j] = __builtin_amdgcn_mfma_f32_16x16x32_bf16(af, b_c[j], acc[j], 0, 0, 0);

        // rotate pipeline
        a0_c = a0_n; a1_c = a1_n;
        a0_n = a0_p; a1_n = a1_p;
        #pragma unroll
        for (int j = 0; j < 6; ++j) b_c[j] = b_n[j];
    }

    // --- reduce per-row stats over the 4 lanes (quads) sharing row m ---
    sum   += __shfl_xor(sum,   16); sum   += __shfl_xor(sum,   32);
    sumsq += __shfl_xor(sumsq, 16); sumsq += __shfl_xor(sumsq, 32);

    // --- AR2 normal-equation sums over the last-150 tail (L1/L2-hot) ---
    const float* ytail = x + (size_t)(row0 + m) * L + (L - MLEN);
    float A11 = 0.f, A22 = 0.f, A12 = 0.f, b1 = 0.f, b2 = 0.f;
    for (int i = quad; i < NAR; i += 4) {
        float p2v = ytail[i];
        float p1v = ytail[i + 1];
        float Yv  = ytail[i + 2];
        A11 = fmaf(p1v, p1v, A11);
        A22 = fmaf(p2v, p2v, A22);
        A12 = fmaf(p1v, p2v, A12);
        b1  = fmaf(p1v, Yv,  b1);
        b2  = fmaf(p2v, Yv,  b2);
    }
    A11 += __shfl_xor(A11, 16); A11 += __shfl_xor(A11, 32);
    A22 += __shfl_xor(A22, 16); A22 += __shfl_xor(A22, 32);
    A12 += __shfl_xor(A12, 16); A12 += __shfl_xor(A12, 32);
    b1  += __shfl_xor(b1,  16); b1  += __shfl_xor(b1,  32);
    b2  += __shfl_xor(b2,  16); b2  += __shfl_xor(b2,  32);

    float lo = 0.f, hi = 0.f;
    if (quad == 0) {                       // lanes 0..15: row m
        A11 += LAM; A22 += LAM;
        float det = A11 * A22 - A12 * A12;
        float a1c = (b1 * A22 - b2 * A12) / det;
        float a2c = (A11 * b2 - A12 * b1) / det;

        float last = ytail[MLEN - 1];
        float y1 = last;
        float y2 = ytail[MLEN - 2];
        for (int n = 0; n < NH; ++n) {
            float yn = a1c * y1 + a2c * y2;
            Ys[m][n] = yn;
            y2 = y1; y1 = yn;
        }
        float var  = (sumsq - sum * sum * (1.0f / L)) * (1.0f / (L - 1));
        float hstd = fmaxf(sqrtf(fmaxf(var, 0.f)), 1e-6f);
        lo = last - CLIP_K * hstd;
        hi = last + CLIP_K * hstd;
    }
    __syncthreads();   // single wave: just orders LDS writes before reads

    // --- epilogue: out = clip(Yb + d_hat, lo, hi) ---
    #pragma unroll
    for (int reg = 0; reg < 4; ++reg) {
        int r = quad * 4 + reg;            // local row of this C element
        float rlo = __shfl(lo, r);         // from lane r (computed above)
        float rhi = __shfl(hi, r);
        #pragma unroll
        for (int j = 0; j < 6; ++j) {
            int c = 16 * j + m;
            float v = acc[j][reg] + Ys[r][c];
            v = fminf(fmaxf(v, rlo), rhi);
            out[(size_t)(row0 + r) * NH + c] = v;
        }
    }
}

extern "C" void kernel_launch(void* const* d_in, const int* in_sizes, int n_in,
                              void* d_out, int out_size, void* d_ws, size_t ws_size,
                              hipStream_t stream) {
    const float* x = (const float*)d_in[0];   // (32,512,2048) fp32
    const float* W = (const float*)d_in[1];   // (2048,96) fp32
    float* out = (float*)d_out;               // (32,512,96) fp32
    short* Wt  = (short*)d_ws;                // 96*2048 bf16 = 384 KB scratch

    // 1) W -> bf16 transposed (Wt[n][k])
    wt_kernel<<<dim3((NH * L) / 256), dim3(256), 0, stream>>>(W, Wt);

    // 2) fused GEMM + AR2 + clip: one wave per 16 rows
    const int rows = 32 * 512;                // 16384
    gemm_ar2_kernel<<<dim3(rows / 16), dim3(64), 0, stream>>>(x, Wt, out);
}